// Round 6
// baseline (551.378 us; speedup 1.0000x reference)
//
#include <hip/hip_runtime.h>
#include <hip/hip_fp16.h>

// GCN: out = relu( (X[i] + sum_{j in N(i)} X[j]) / deg[i] @ W )
// Pipeline (5 kernels):
//   setup:   zero bucket cursors + edge-dtype detect + W->MFMA-frag pack
//   scatter: bucket edges by (node>>7), block-aggregated reservations
//   sortwin: per-bucket counting sort by (owner_local, neighbor>>13)
//            -> adjacency sorted by NEIGHBOR WINDOW (8192 nodes = 2 MB of Yh
//            per window, fits 4 MB per-XCD L2). Writes adj in-place over
//            bucket, per-(node,window) {start,len} descriptors, per-node deg.
//   gemm:    Y = X@W via mfma_f32_16x16x32_bf16, Y stored fp16
//   gatherw: PERSISTENT window-swept gather: 6144 waves (= 24 waves/CU,
//            fully resident), wave owns 17 nodes w/ half2 accs in registers
//            (static unroll). Outer loop over 13 windows keeps ALL waves
//            reading the same 2 MB slice of Yh concurrently -> L2-hit
//            gather instead of random L2-miss gather (the round-5 wall).

#define DFEAT 128
#define BSH 7
#define BNODES (1 << BSH)   // 128 nodes per bucket
#define NBMAX 800           // >= ceil(100000/128)=782
#define EPT_SC 4            // edges per thread in scatter
#define EPB (1024 * EPT_SC) // 4096 edges per block
#define SORT_CAP 6144       // per-bucket capacity (mean 4096, sd 64)
#define WSH 13              // window = neighbor >> 13 (8192 nodes = 2 MB Yh)
#define NWSLOT 16           // descriptor slots per node (13 used)
#define KBINS (BNODES * NWSLOT)  // 2048 sort bins
#define NPW 17              // nodes per wave in gatherw
#define GBLK 1536           // 6144 waves; 6144*17=104448 >= n

typedef __attribute__((ext_vector_type(8))) short short8;
typedef __attribute__((ext_vector_type(4))) float f32x4;

__device__ __forceinline__ unsigned short f2bf(float x) {  // RNE
  unsigned u = __float_as_uint(x);
  return (unsigned short)((u + 0x7FFFu + ((u >> 16) & 1u)) >> 16);
}
__device__ __forceinline__ __half2 u2h(unsigned x) {
  union { unsigned u; __half2 h; } c; c.u = x; return c.h;
}

// ---------------- setup: zero cursors + dtype detect + wfrag ----------------
__global__ __launch_bounds__(256) void setup_kernel(const int* el32, int* gcur,
                                                    int* flag,
                                                    const float* __restrict__ W,
                                                    unsigned int* __restrict__ Wfrag) {
  int e = blockIdx.x * 256 + threadIdx.x;  // 0..2047
  if (e < NBMAX) gcur[e] = 0;
  if (e == 0) flag[0] = (el32[1] == 0 && el32[3] == 0) ? 1 : 0;
  if (e < 2048) {
    int lane = e & 63;
    int nt = (e >> 6) & 7;
    int kc = e >> 9;
    int k0 = kc * 32 + (lane >> 4) * 8;
    int col = nt * 16 + (lane & 15);
    unsigned int o[4];
#pragma unroll
    for (int jj = 0; jj < 4; jj++) {
      unsigned short lo = f2bf(W[(k0 + 2 * jj) * DFEAT + col]);
      unsigned short hi = f2bf(W[(k0 + 2 * jj + 1) * DFEAT + col]);
      o[jj] = (unsigned)lo | ((unsigned)hi << 16);
    }
    uint4* dst = (uint4*)Wfrag;
    uint4 v; v.x = o[0]; v.y = o[1]; v.z = o[2]; v.w = o[3];
    dst[e] = v;
  }
}

__device__ __forceinline__ int edge_at(const void* el, long long i, int mode64) {
  if (mode64) return (int)((const long long*)el)[i];
  return ((const int*)el)[i];
}

// ---------------- block-aggregated bucketed scatter (4 edges/thread) -------
// Entry: (owner_local << 20) | neighbor   (n < 2^20)
__global__ __launch_bounds__(1024) void scatter_kernel(const void* el,
                                                       const int* __restrict__ flag,
                                                       int* __restrict__ gcur,
                                                       unsigned int* __restrict__ bucket,
                                                       int E, int NB) {
  __shared__ int lh[NBMAX];   // local counts, then local cursors
  __shared__ int lb[NBMAX];   // reserved bases within bucket region
  int t = threadIdx.x;
  for (int i = t; i < NB; i += 1024) lh[i] = 0;
  __syncthreads();
  int m = flag[0];
  long long e0 = (long long)blockIdx.x * EPB + t;
  int s[EPT_SC], d[EPT_SC];
#pragma unroll
  for (int r = 0; r < EPT_SC; r++) {
    long long e = e0 + r * 1024;
    if (e < E) {
      s[r] = edge_at(el, e, m);
      d[r] = edge_at(el, (long long)E + e, m);
    } else {
      s[r] = -1;
    }
  }
#pragma unroll
  for (int r = 0; r < EPT_SC; r++) {
    if (s[r] >= 0) {
      atomicAdd(&lh[s[r] >> BSH], 1);
      atomicAdd(&lh[d[r] >> BSH], 1);
    }
  }
  __syncthreads();
  for (int i = t; i < NB; i += 1024) {
    int c = lh[i];
    lb[i] = c ? atomicAdd(&gcur[i], c) : 0;  // cursors start at 0
  }
  __syncthreads();
  for (int i = t; i < NB; i += 1024) lh[i] = 0;
  __syncthreads();
#pragma unroll
  for (int r = 0; r < EPT_SC; r++) {
    if (s[r] >= 0) {
      int bs = s[r] >> BSH, bd = d[r] >> BSH;
      int ps = lb[bs] + atomicAdd(&lh[bs], 1);
      if (ps < SORT_CAP)
        bucket[(long long)bs * SORT_CAP + ps] =
            ((unsigned)(s[r] & (BNODES - 1)) << 20) | (unsigned)d[r];
      int pd = lb[bd] + atomicAdd(&lh[bd], 1);
      if (pd < SORT_CAP)
        bucket[(long long)bd * SORT_CAP + pd] =
            ((unsigned)(d[r] & (BNODES - 1)) << 20) | (unsigned)s[r];
    }
  }
}

// ---------------- windowed counting sort -> adj (in-place) + pw + deg ------
// Key = owner_local*16 + (neighbor>>13). 2048-bin histogram + scan; adj is
// written back over the bucket region (bucket fully consumed first).
__global__ __launch_bounds__(1024) void sortwin_kernel(unsigned int* __restrict__ bucket,
                                                       const int* __restrict__ gcur,
                                                       int2* __restrict__ pw,
                                                       int* __restrict__ degg,
                                                       int n) {
  __shared__ int srt[SORT_CAP];                  // 24 KB
  __shared__ int h2[KBINS], pr2[KBINS], cur2[KBINS];  // 24 KB
  __shared__ int wsc[1024];                      // 4 KB
  int b = blockIdx.x, t = threadIdx.x;
  int cnt = gcur[b]; if (cnt > SORT_CAP) cnt = SORT_CAP;
  long long base = (long long)b * SORT_CAP;

  h2[t] = 0; h2[t + 1024] = 0;
  __syncthreads();
  for (int i = t; i < cnt; i += 1024) {
    unsigned e = bucket[base + i];
    int key = (int)((e >> 20) << 4) | (int)((e & 0xFFFFFu) >> WSH);
    atomicAdd(&h2[key], 1);
  }
  __syncthreads();
  // exclusive scan over 2048 bins: thread t owns bins 2t, 2t+1
  int a0 = h2[2 * t], a1 = h2[2 * t + 1];
  int s = a0 + a1;
  wsc[t] = s;
  __syncthreads();
  for (int dd = 1; dd < 1024; dd <<= 1) {
    int aa = (t >= dd) ? wsc[t - dd] : 0;
    __syncthreads();
    wsc[t] += aa;
    __syncthreads();
  }
  int excl = wsc[t] - s;
  pr2[2 * t] = excl;          cur2[2 * t] = excl;
  pr2[2 * t + 1] = excl + a0; cur2[2 * t + 1] = excl + a0;
  __syncthreads();
  for (int i = t; i < cnt; i += 1024) {
    unsigned e = bucket[base + i];
    int key = (int)((e >> 20) << 4) | (int)((e & 0xFFFFFu) >> WSH);
    int p = atomicAdd(&cur2[key], 1);
    srt[p] = (int)(e & 0xFFFFFu);
  }
  __syncthreads();
  // bucket fully consumed -> write sorted adjacency in-place
  for (int i = t; i < cnt; i += 1024) bucket[base + i] = (unsigned)srt[i];
  // per-(node,window) descriptors + per-node degree
  int node0 = b << BSH;
  for (int i = t; i < KBINS; i += 1024) {
    int node = node0 + (i >> 4);
    if (node < n)
      pw[((long long)node << 4) | (i & 15)] =
          make_int2((int)(base + pr2[i]), h2[i]);
  }
  if (t < BNODES) {
    int node = node0 + t;
    if (node < n) {
      int sdeg = 0;
#pragma unroll
      for (int d2 = 0; d2 < NWSLOT; d2++) sdeg += h2[(t << 4) | d2];
      degg[node] = sdeg;
    }
  }
}

// ---------------- Y = X @ W via MFMA bf16, output fp16 ----------------
__global__ __launch_bounds__(256) void gemm_kernel(const float* __restrict__ X,
                                                   const short8* __restrict__ Wfrag,
                                                   __half* __restrict__ Yh, int n) {
  int wave = threadIdx.x >> 6;
  int lane = threadIdx.x & 63;
  int row0 = (blockIdx.x * 4 + wave) * 16;
  if (row0 >= n) return;

  int rowA = row0 + (lane & 15);
  if (rowA >= n) rowA = n - 1;  // duplicate last row; stores guarded
  const float4* Xrow = (const float4*)(X + (long long)rowA * DFEAT);
  int koff = (lane >> 4) * 2;

  f32x4 acc[8];
#pragma unroll
  for (int ntp = 0; ntp < 8; ntp++) acc[ntp] = (f32x4){0.f, 0.f, 0.f, 0.f};

#pragma unroll
  for (int kc = 0; kc < 4; kc++) {
    float4 xa = Xrow[kc * 8 + koff];
    float4 xb = Xrow[kc * 8 + koff + 1];
    short8 a8;
    a8[0] = (short)f2bf(xa.x); a8[1] = (short)f2bf(xa.y);
    a8[2] = (short)f2bf(xa.z); a8[3] = (short)f2bf(xa.w);
    a8[4] = (short)f2bf(xb.x); a8[5] = (short)f2bf(xb.y);
    a8[6] = (short)f2bf(xb.z); a8[7] = (short)f2bf(xb.w);
#pragma unroll
    for (int nt = 0; nt < 8; nt++) {
      short8 b8 = Wfrag[(kc * 8 + nt) * 64 + lane];
      acc[nt] = __builtin_amdgcn_mfma_f32_16x16x32_bf16(a8, b8, acc[nt], 0, 0, 0);
    }
  }

  int rbase = row0 + (lane >> 4) * 4;
  int cbase = lane & 15;
#pragma unroll
  for (int nt = 0; nt < 8; nt++) {
#pragma unroll
    for (int r = 0; r < 4; r++) {
      int row = rbase + r;
      if (row < n)
        Yh[(long long)row * DFEAT + nt * 16 + cbase] = __float2half(acc[nt][r]);
    }
  }
}

// ---------------- persistent window-swept gather + scale + relu -----------
// 6144 waves (1536 blocks x 4), all resident at 24 waves/CU. Wave owns 17
// consecutive nodes; half2 accumulator per node in registers (static
// unroll). Outer loop over neighbor windows keeps every resident wave
// reading the same 2 MB slice of Yh -> L2 hits instead of random misses.
__global__ __launch_bounds__(256, 6) void gatherw_kernel(
    const unsigned int* __restrict__ Yh,   // half2 view
    const int2* __restrict__ pw,
    const int* __restrict__ degg,
    const unsigned int* __restrict__ adj,
    float2* __restrict__ out2, int n) {
  int g = (int)((blockIdx.x * (long long)blockDim.x + threadIdx.x) >> 6);
  int lane = threadIdx.x & 63;
  int nb0 = g * NPW;
  if (nb0 >= n) return;
  int nwin = (n + (1 << WSH) - 1) >> WSH;  // 13

  __half2 acc[NPW];
#pragma unroll
  for (int k = 0; k < NPW; k++) {
    int nd = nb0 + k;
    acc[k] = (nd < n) ? u2h(Yh[(long long)nd * 64 + lane]) : u2h(0u);  // self
  }

  for (int d = 0; d < nwin; d++) {
#pragma unroll
    for (int k = 0; k < NPW; k++) {
      int nd = nb0 + k;
      if (nd >= n) continue;
      int2 sl = pw[((long long)nd << 4) | d];
      int st = sl.x, ln = sl.y;
      for (int bb = 0; bb < ln; bb += 64) {
        int c2 = ln - bb; if (c2 > 64) c2 = 64;
        int idx = (lane < c2) ? (int)adj[st + bb + lane] : 0;
        for (int tt = 0; tt < c2; tt++) {
          int j = __shfl(idx, tt);
          acc[k] = __hadd2(acc[k], u2h(Yh[(long long)j * 64 + lane]));
        }
      }
    }
  }

#pragma unroll
  for (int k = 0; k < NPW; k++) {
    int nd = nb0 + k;
    if (nd >= n) continue;
    float2 f = __half22float2(acc[k]);
    float inv = 1.0f / (float)degg[nd];
    float2 o;
    o.x = f.x * inv;
    o.y = f.y * inv;
    o.x = o.x > 0.f ? o.x : 0.f;
    o.y = o.y > 0.f ? o.y : 0.f;
    out2[(long long)nd * 64 + lane] = o;
  }
}

// ---------------- launch ----------------
extern "C" void kernel_launch(void* const* d_in, const int* in_sizes, int n_in,
                              void* d_out, int out_size, void* d_ws, size_t ws_size,
                              hipStream_t stream) {
  const float* X = (const float*)d_in[0];
  const float* W = (const float*)d_in[1];
  const void* el = d_in[2];
  float* out = (float*)d_out;

  int n = in_sizes[0] / DFEAT;       // 100000
  int E = in_sizes[2] / 2;           // 1600000
  int NB = (n + BNODES - 1) >> BSH;  // 782

  char* p = (char*)d_ws;
  auto alloc = [&](size_t bytes) -> char* {
    char* q = p;
    p += (bytes + 511) & ~(size_t)511;
    return q;
  };
  int* gcur = (int*)alloc((size_t)NBMAX * 4);
  int* flag = (int*)alloc(64);
  unsigned int* bucket = (unsigned int*)alloc((size_t)NBMAX * SORT_CAP * 4);
  int2* pw   = (int2*)alloc((size_t)n * NWSLOT * 8);
  int* degg  = (int*)alloc((size_t)n * 4);
  unsigned int* Wfrag = (unsigned int*)alloc((size_t)2048 * 16);
  __half* Yh = (__half*)alloc((size_t)n * DFEAT * 2);

  int eblocks = (E + EPB - 1) / EPB;

  setup_kernel<<<8, 256, 0, stream>>>((const int*)el, gcur, flag, W, Wfrag);
  scatter_kernel<<<eblocks, 1024, 0, stream>>>(el, flag, gcur, bucket, E, NB);
  sortwin_kernel<<<NB, 1024, 0, stream>>>(bucket, gcur, pw, degg, n);
  gemm_kernel<<<(n + 63) / 64, 256, 0, stream>>>(X, (const short8*)Wfrag, Yh, n);
  gatherw_kernel<<<GBLK, 256, 0, stream>>>((const unsigned int*)Yh, pw, degg,
                                           bucket, (float2*)out, n);
}

// Round 8
// 273.720 us; speedup vs baseline: 2.0144x; 2.0144x over previous
//
#include <hip/hip_runtime.h>
#include <hip/hip_fp16.h>

// GCN: out = relu( (X[i] + sum_{j in N(i)} X[j]) / deg[i] @ W )
// Pipeline (4 kernels + 1 memset):
//   memset:  zero per-bucket SLOT cursors
//   scatter: FULL-LINE bucketed scatter. Per block: LDS counting-sort of its
//            16384 entries by bucket, per-(block,bucket) space reserved in
//            32-entry (128 B) ALIGNED slots via global slot cursor, flushed
//            with consecutive-lane full-line stores (sentinel-padded).
//            Round-2 counters proved partial-line masked writes run at
//            ~0.7 TB/s (187 MB for 12.8 MB logical) -> old scatter ~100 us.
//            Block 0 also packs W into the MFMA B-fragment (wfrag folded).
//   sort:    per-bucket counting sort (skips sentinels) -> adj + start/deg
//   gemm:    Y = X@W via mfma_f32_16x16x32_bf16, Y stored fp16
//   gather:  one wave per node, split-wave uint2 loads (proven 106 us).

#define DFEAT 128
#define BSH 7
#define BNODES (1 << BSH)    // 128 nodes per bucket
#define NBMAX 784            // >= ceil(100000/128)=782
#define EPB 8192             // edges per block in scatter (8/thread)
#define ENTB (2 * EPB)       // 16384 entries per block
#define SLOT_CAPS 256        // slots per bucket (32 entries each)
#define BCAP (SLOT_CAPS * 32)  // 8192 entries of padded bucket region
#define SORT_CAP 6144        // valid-entry capacity (mean 4096, sd 64)
#define SENT 0xFFFFFFFFu

typedef __attribute__((ext_vector_type(8))) short short8;
typedef __attribute__((ext_vector_type(4))) float f32x4;

__device__ __forceinline__ unsigned short f2bf(float x) {  // RNE
  unsigned u = __float_as_uint(x);
  return (unsigned short)((u + 0x7FFFu + ((u >> 16) & 1u)) >> 16);
}
__device__ __forceinline__ __half2 u2h(unsigned x) {
  union { unsigned u; __half2 h; } c; c.u = x; return c.h;
}
__device__ __forceinline__ unsigned h2u(__half2 x) {
  union { __half2 h; unsigned u; } c; c.h = x; return c.u;
}

__device__ __forceinline__ int edge_at(const void* el, long long i, int mode64) {
  if (mode64) return (int)((const long long*)el)[i];
  return ((const int*)el)[i];
}

// ---------------- full-line bucketed scatter (8 edges/thread) -------------
// Entry payload: (owner_local << 20) | neighbor   (n < 2^20)
__global__ __launch_bounds__(1024) void scatter_kernel(const void* el,
                                                       int* __restrict__ scur,
                                                       unsigned int* __restrict__ bucket,
                                                       const float* __restrict__ W,
                                                       unsigned int* __restrict__ Wfrag,
                                                       int E, int NB) {
  __shared__ unsigned staged[ENTB];          // 64 KB
  __shared__ int lh[NBMAX], lbase[NBMAX], gbe[NBMAX];  // 9.2 KB
  __shared__ int scanbuf[1024];              // 4 KB (scan, then cursors)
  int t = threadIdx.x;

  // ---- wfrag (block 0 only; regs/global only, no LDS interference) ----
  if (blockIdx.x == 0) {
#pragma unroll
    for (int rr = 0; rr < 2; rr++) {
      int e = t + rr * 1024;  // 0..2047
      int lane = e & 63;
      int nt = (e >> 6) & 7;
      int kc = e >> 9;
      int k0 = kc * 32 + (lane >> 4) * 8;
      int col = nt * 16 + (lane & 15);
      unsigned int o[4];
#pragma unroll
      for (int jj = 0; jj < 4; jj++) {
        unsigned short lo = f2bf(W[(k0 + 2 * jj) * DFEAT + col]);
        unsigned short hi = f2bf(W[(k0 + 2 * jj + 1) * DFEAT + col]);
        o[jj] = (unsigned)lo | ((unsigned)hi << 16);
      }
      uint4* dst = (uint4*)Wfrag;
      uint4 v; v.x = o[0]; v.y = o[1]; v.z = o[2]; v.w = o[3];
      dst[e] = v;
    }
  }

  const int* el32 = (const int*)el;
  int m = (el32[1] == 0 && el32[3] == 0) ? 1 : 0;  // dtype detect (uniform)

  for (int i = t; i < NB; i += 1024) lh[i] = 0;
  __syncthreads();

  long long e0 = (long long)blockIdx.x * EPB + t;
  int s[8], d[8];
#pragma unroll
  for (int r = 0; r < 8; r++) {
    long long e = e0 + r * 1024;
    if (e < E) {
      s[r] = edge_at(el, e, m);
      d[r] = edge_at(el, (long long)E + e, m);
    } else {
      s[r] = -1;
    }
  }
#pragma unroll
  for (int r = 0; r < 8; r++) {
    if (s[r] >= 0) {
      atomicAdd(&lh[s[r] >> BSH], 1);
      atomicAdd(&lh[d[r] >> BSH], 1);
    }
  }
  __syncthreads();

  // exclusive scan of lh -> lbase (local compact layout)
  int v = (t < NB) ? lh[t] : 0;
  scanbuf[t] = v;
  __syncthreads();
  for (int dd = 1; dd < 1024; dd <<= 1) {
    int a = (t >= dd) ? scanbuf[t - dd] : 0;
    __syncthreads();
    scanbuf[t] += a;
    __syncthreads();
  }
  if (t < NB) lbase[t] = scanbuf[t] - v;
  // global slot reservation (128 B aligned chunks)
  if (t < NB) {
    int slots = (v + 31) >> 5;
    gbe[t] = slots ? (atomicAdd(&scur[t], slots) << 5) : 0;  // entry offset in bucket
  }
  __syncthreads();
  scanbuf[t] = 0;  // reuse as per-bucket cursors
  __syncthreads();

  // place entries into LDS staged[], compact by bucket
#pragma unroll
  for (int r = 0; r < 8; r++) {
    if (s[r] >= 0) {
      int bs = s[r] >> BSH, bd = d[r] >> BSH;
      int ps = lbase[bs] + atomicAdd(&scanbuf[bs], 1);
      staged[ps] = ((unsigned)(s[r] & (BNODES - 1)) << 20) | (unsigned)d[r];
      int pd = lbase[bd] + atomicAdd(&scanbuf[bd], 1);
      staged[pd] = ((unsigned)(d[r] & (BNODES - 1)) << 20) | (unsigned)s[r];
    }
  }
  __syncthreads();

  // flush: wave w handles buckets w, w+16, ... ; full-line aligned stores
  int wave = t >> 6, lane = t & 63;
  for (int i = wave; i < NB; i += 16) {
    int cnt = lh[i];
    if (cnt == 0) continue;
    int lb = lbase[i], gb = gbe[i];
    int padded = ((cnt + 31) >> 5) << 5;
    long long bb = (long long)i * BCAP;
    for (int j = lane; j < padded; j += 64) {
      if (gb + j < BCAP)
        bucket[bb + gb + j] = (j < cnt) ? staged[lb + j] : SENT;
    }
  }
}

// ---------------- per-bucket counting sort (skip sentinels) ---------------
__global__ __launch_bounds__(1024) void sort_kernel(const unsigned int* __restrict__ bucket,
                                                    const int* __restrict__ scur,
                                                    int* __restrict__ adj,
                                                    int* __restrict__ start,
                                                    int* __restrict__ degg,
                                                    int n) {
  __shared__ int srt[SORT_CAP];  // 24 KB
  __shared__ int h[BNODES], pref[BNODES], cur[BNODES], scn[BNODES];
  int b = blockIdx.x, t = threadIdx.x;
  int slots = scur[b]; if (slots > SLOT_CAPS) slots = SLOT_CAPS;
  int cnt = slots << 5;
  long long base = (long long)b * BCAP;

  if (t < BNODES) h[t] = 0;
  __syncthreads();
  for (int i = t; i < cnt; i += 1024) {
    unsigned e = bucket[base + i];
    if (e != SENT) atomicAdd(&h[e >> 20], 1);
  }
  __syncthreads();
  int v = (t < BNODES) ? h[t] : 0;
  if (t < BNODES) scn[t] = v;
  __syncthreads();
  for (int dd = 1; dd < BNODES; dd <<= 1) {
    int a = (t < BNODES && t >= dd) ? scn[t - dd] : 0;
    __syncthreads();
    if (t < BNODES) scn[t] += a;
    __syncthreads();
  }
  if (t < BNODES) { pref[t] = scn[t] - v; cur[t] = scn[t] - v; }
  __syncthreads();
  for (int i = t; i < cnt; i += 1024) {
    unsigned e = bucket[base + i];
    if (e != SENT) {
      int p = atomicAdd(&cur[e >> 20], 1);
      if (p < SORT_CAP) srt[p] = (int)(e & 0xFFFFFu);
    }
  }
  __syncthreads();
  int total = scn[BNODES - 1]; if (total > SORT_CAP) total = SORT_CAP;
  long long abase = (long long)b * SORT_CAP;
  for (int i = t; i < total; i += 1024) adj[abase + i] = srt[i];
  int node = (b << BSH) + t;
  if (t < BNODES && node < n) {
    start[node] = (int)(abase + pref[t]);
    degg[node] = h[t];
  }
}

// ---------------- Y = X @ W via MFMA bf16, output fp16 ----------------
__global__ __launch_bounds__(256) void gemm_kernel(const float* __restrict__ X,
                                                   const short8* __restrict__ Wfrag,
                                                   __half* __restrict__ Yh, int n) {
  int wave = threadIdx.x >> 6;
  int lane = threadIdx.x & 63;
  int row0 = (blockIdx.x * 4 + wave) * 16;
  if (row0 >= n) return;

  int rowA = row0 + (lane & 15);
  if (rowA >= n) rowA = n - 1;  // duplicate last row; stores guarded
  const float4* Xrow = (const float4*)(X + (long long)rowA * DFEAT);
  int koff = (lane >> 4) * 2;

  f32x4 acc[8];
#pragma unroll
  for (int ntp = 0; ntp < 8; ntp++) acc[ntp] = (f32x4){0.f, 0.f, 0.f, 0.f};

#pragma unroll
  for (int kc = 0; kc < 4; kc++) {
    float4 xa = Xrow[kc * 8 + koff];
    float4 xb = Xrow[kc * 8 + koff + 1];
    short8 a8;
    a8[0] = (short)f2bf(xa.x); a8[1] = (short)f2bf(xa.y);
    a8[2] = (short)f2bf(xa.z); a8[3] = (short)f2bf(xa.w);
    a8[4] = (short)f2bf(xb.x); a8[5] = (short)f2bf(xb.y);
    a8[6] = (short)f2bf(xb.z); a8[7] = (short)f2bf(xb.w);
#pragma unroll
    for (int nt = 0; nt < 8; nt++) {
      short8 b8 = Wfrag[(kc * 8 + nt) * 64 + lane];
      acc[nt] = __builtin_amdgcn_mfma_f32_16x16x32_bf16(a8, b8, acc[nt], 0, 0, 0);
    }
  }

  int rbase = row0 + (lane >> 4) * 4;
  int cbase = lane & 15;
#pragma unroll
  for (int nt = 0; nt < 8; nt++) {
#pragma unroll
    for (int r = 0; r < 4; r++) {
      int row = rbase + r;
      if (row < n)
        Yh[(long long)row * DFEAT + nt * 16 + cbase] = __float2half(acc[nt][r]);
    }
  }
}

// ---------------- gather + scale + relu (split-wave uint2 loads) ----------
__global__ __launch_bounds__(256) void gather_kernel(const uint2* __restrict__ Yh2,
                                                     const int* __restrict__ start,
                                                     const int* __restrict__ degg,
                                                     const int* __restrict__ adj,
                                                     float4* __restrict__ out4, int n) {
  int wid = (int)((blockIdx.x * (long long)blockDim.x + threadIdx.x) >> 6);
  int lane = threadIdx.x & 63;
  if (wid >= n) return;

  int off0 = start[wid], len = degg[wid];
  int c = lane & 31;
  int half = lane >> 5;
  __half2 acc0 = u2h(0), acc1 = u2h(0), acc2 = u2h(0), acc3 = u2h(0);

  for (int base = 0; base < len; base += 64) {
    int cnt = len - base; if (cnt > 64) cnt = 64;
    int idx = (lane < cnt) ? adj[off0 + base + lane] : 0;
    int tt = 0;
    for (; tt + 16 <= cnt; tt += 16) {  // 16 rows per iter, 8 loads in flight
      uint2 v[8];
#pragma unroll
      for (int u = 0; u < 8; u++) {
        int j = __shfl(idx, tt + 2 * u + half);
        v[u] = Yh2[(long long)j * 32 + c];
      }
      acc0 = __hadd2(acc0, u2h(v[0].x)); acc1 = __hadd2(acc1, u2h(v[0].y));
      acc2 = __hadd2(acc2, u2h(v[1].x)); acc3 = __hadd2(acc3, u2h(v[1].y));
      acc0 = __hadd2(acc0, u2h(v[2].x)); acc1 = __hadd2(acc1, u2h(v[2].y));
      acc2 = __hadd2(acc2, u2h(v[3].x)); acc3 = __hadd2(acc3, u2h(v[3].y));
      acc0 = __hadd2(acc0, u2h(v[4].x)); acc1 = __hadd2(acc1, u2h(v[4].y));
      acc2 = __hadd2(acc2, u2h(v[5].x)); acc3 = __hadd2(acc3, u2h(v[5].y));
      acc0 = __hadd2(acc0, u2h(v[6].x)); acc1 = __hadd2(acc1, u2h(v[6].y));
      acc2 = __hadd2(acc2, u2h(v[7].x)); acc3 = __hadd2(acc3, u2h(v[7].y));
    }
    for (; tt + 2 <= cnt; tt += 2) {  // pair tail
      int j = __shfl(idx, tt + half);
      uint2 v = Yh2[(long long)j * 32 + c];
      acc0 = __hadd2(acc0, u2h(v.x)); acc1 = __hadd2(acc1, u2h(v.y));
    }
    if (tt < cnt) {  // odd tail: both halves load same row; zero the upper
      int j = __shfl(idx, tt);
      uint2 v = Yh2[(long long)j * 32 + c];
      if (half) { v.x = 0; v.y = 0; }
      acc2 = __hadd2(acc2, u2h(v.x)); acc3 = __hadd2(acc3, u2h(v.y));
    }
  }

  acc0 = __hadd2(acc0, acc2);
  acc1 = __hadd2(acc1, acc3);
  // merge the two half-wave partial sums
  acc0 = __hadd2(acc0, u2h((unsigned)__shfl_xor((int)h2u(acc0), 32)));
  acc1 = __hadd2(acc1, u2h((unsigned)__shfl_xor((int)h2u(acc1), 32)));
  // self row
  uint2 sv = Yh2[(long long)wid * 32 + c];
  acc0 = __hadd2(acc0, u2h(sv.x));
  acc1 = __hadd2(acc1, u2h(sv.y));

  if (half == 0) {
    float2 f0 = __half22float2(acc0);
    float2 f1 = __half22float2(acc1);
    float inv = 1.0f / (float)len;
    float4 o;
    o.x = f0.x * inv; o.y = f0.y * inv; o.z = f1.x * inv; o.w = f1.y * inv;
    o.x = o.x > 0.f ? o.x : 0.f;
    o.y = o.y > 0.f ? o.y : 0.f;
    o.z = o.z > 0.f ? o.z : 0.f;
    o.w = o.w > 0.f ? o.w : 0.f;
    out4[(long long)wid * 32 + c] = o;
  }
}

// ---------------- launch ----------------
extern "C" void kernel_launch(void* const* d_in, const int* in_sizes, int n_in,
                              void* d_out, int out_size, void* d_ws, size_t ws_size,
                              hipStream_t stream) {
  const float* X = (const float*)d_in[0];
  const float* W = (const float*)d_in[1];
  const void* el = d_in[2];
  float* out = (float*)d_out;

  int n = in_sizes[0] / DFEAT;       // 100000
  int E = in_sizes[2] / 2;           // 1600000
  int NB = (n + BNODES - 1) >> BSH;  // 782

  char* p = (char*)d_ws;
  auto alloc = [&](size_t bytes) -> char* {
    char* q = p;
    p += (bytes + 511) & ~(size_t)511;
    return q;
  };
  int* scur = (int*)alloc((size_t)NBMAX * 4);
  unsigned int* bucket = (unsigned int*)alloc((size_t)NBMAX * BCAP * 4);   // 25.7 MB
  int* adj   = (int*)alloc((size_t)NBMAX * SORT_CAP * 4);                  // 19.3 MB
  int* start = (int*)alloc((size_t)n * 4);
  int* degg  = (int*)alloc((size_t)n * 4);
  unsigned int* Wfrag = (unsigned int*)alloc((size_t)2048 * 16);
  __half* Yh = (__half*)alloc((size_t)n * DFEAT * 2);

  int eblocks = (E + EPB - 1) / EPB;  // 196

  hipMemsetAsync(scur, 0, (size_t)NBMAX * 4, stream);
  scatter_kernel<<<eblocks, 1024, 0, stream>>>(el, scur, bucket, W, Wfrag, E, NB);
  sort_kernel<<<NB, 1024, 0, stream>>>(bucket, scur, adj, start, degg, n);
  gemm_kernel<<<(n + 63) / 64, 256, 0, stream>>>(X, (const short8*)Wfrag, Yh, n);
  gather_kernel<<<(n + 3) / 4, 256, 0, stream>>>((const uint2*)Yh, start, degg, adj,
                                                 (float4*)out, n);
}

// Round 10
// 252.466 us; speedup vs baseline: 2.1840x; 1.0842x over previous
//
#include <hip/hip_runtime.h>
#include <hip/hip_fp16.h>

// GCN: out = relu( (X[i] + sum_{j in N(i)} X[j]) / deg[i] @ W )
// Pipeline (3 kernels + 1 memset) -- launch-gap reduction WITHOUT grid.sync:
//   memset: zero bucket cursors
//   work:   FAT kernel, 512-thr blocks. Blocks [0,SBLKS): round-5 bucketed
//           scatter (8 edges/thread). Blocks [SBLKS,+GBLKS): MFMA gemm,
//           128 rows/block, W packed to LDS per block (wfrag kernel gone).
//           Scatter(VMEM) and gemm(MFMA/VALU) co-reside 2 blocks/CU ->
//           gemm hides under scatter (m114 mechanism), ~28us + 2 gaps saved.
//   sort:   per-bucket counting sort -> adj + start/deg   (proven ~13us)
//   gather: split-wave uint2 gather                        (proven ~106us)

#define DFEAT 128
#define BSH 7
#define BNODES (1 << BSH)    // 128 nodes per bucket
#define NBMAX 784            // >= ceil(100000/128)=782
#define EPT_SC 8             // edges per thread in scatter (512 thr)
#define EPB (512 * EPT_SC)   // 4096 edges per scatter block
#define SORT_CAP 6144        // per-bucket capacity (mean 4096, sd 64)
#define GROWS 128            // rows per gemm block (8 waves x 16)

typedef __attribute__((ext_vector_type(8))) short short8;
typedef __attribute__((ext_vector_type(4))) float f32x4;

__device__ __forceinline__ unsigned short f2bf(float x) {  // RNE
  unsigned u = __float_as_uint(x);
  return (unsigned short)((u + 0x7FFFu + ((u >> 16) & 1u)) >> 16);
}
__device__ __forceinline__ __half2 u2h(unsigned x) {
  union { unsigned u; __half2 h; } c; c.u = x; return c.h;
}
__device__ __forceinline__ unsigned h2u(__half2 x) {
  union { __half2 h; unsigned u; } c; c.h = x; return c.u;
}
__device__ __forceinline__ int edge_at(const void* el, long long i, int mode64) {
  if (mode64) return (int)((const long long*)el)[i];
  return ((const int*)el)[i];
}

union SMemW {
  struct { int lh[NBMAX]; int lb[NBMAX]; } sc;  // scatter: 6.3 KB
  uint4 wf[2048];                               // gemm: W-fragment, 32 KB
};

// ---------------- fat kernel: scatter blocks + gemm blocks ----------------
__global__ __launch_bounds__(512, 4) void work_kernel(
    const void* el, int* __restrict__ gcur, unsigned int* __restrict__ bucket,
    const float* __restrict__ X, const float* __restrict__ W,
    __half* __restrict__ Yh, int E, int n, int NB, int SBLKS) {
  __shared__ SMemW sm;
  int t = threadIdx.x;

  if ((int)blockIdx.x < SBLKS) {
    // ---------------- scatter (round-5 proven form) ----------------
    const int* el32 = (const int*)el;
    int m = (el32[1] == 0 && el32[3] == 0) ? 1 : 0;  // int64 vs int32
    for (int i = t; i < NB; i += 512) sm.sc.lh[i] = 0;
    __syncthreads();
    long long e0 = (long long)blockIdx.x * EPB + t;
    int s[EPT_SC], d[EPT_SC];
#pragma unroll
    for (int r = 0; r < EPT_SC; r++) {
      long long e = e0 + r * 512;
      if (e < E) {
        s[r] = edge_at(el, e, m);
        d[r] = edge_at(el, (long long)E + e, m);
      } else {
        s[r] = -1;
      }
    }
#pragma unroll
    for (int r = 0; r < EPT_SC; r++) {
      if (s[r] >= 0) {
        atomicAdd(&sm.sc.lh[s[r] >> BSH], 1);
        atomicAdd(&sm.sc.lh[d[r] >> BSH], 1);
      }
    }
    __syncthreads();
    for (int i = t; i < NB; i += 512) {
      int c = sm.sc.lh[i];
      sm.sc.lb[i] = c ? atomicAdd(&gcur[i], c) : 0;
    }
    __syncthreads();
    for (int i = t; i < NB; i += 512) sm.sc.lh[i] = 0;
    __syncthreads();
#pragma unroll
    for (int r = 0; r < EPT_SC; r++) {
      if (s[r] >= 0) {
        int bs = s[r] >> BSH, bd = d[r] >> BSH;
        int ps = sm.sc.lb[bs] + atomicAdd(&sm.sc.lh[bs], 1);
        if (ps < SORT_CAP)
          bucket[(long long)bs * SORT_CAP + ps] =
              ((unsigned)(s[r] & (BNODES - 1)) << 20) | (unsigned)d[r];
        int pd = sm.sc.lb[bd] + atomicAdd(&sm.sc.lh[bd], 1);
        if (pd < SORT_CAP)
          bucket[(long long)bd * SORT_CAP + pd] =
              ((unsigned)(d[r] & (BNODES - 1)) << 20) | (unsigned)s[r];
      }
    }
  } else {
    // ---------------- gemm (W packed into LDS per block) ----------------
    int gb = blockIdx.x - SBLKS;
    for (int e = t; e < 2048; e += 512) {
      int l = e & 63;
      int nt = (e >> 6) & 7;
      int kc = e >> 9;
      int k0 = kc * 32 + (l >> 4) * 8;
      int col = nt * 16 + (l & 15);
      unsigned int o[4];
#pragma unroll
      for (int jj = 0; jj < 4; jj++) {
        unsigned short lo = f2bf(W[(k0 + 2 * jj) * DFEAT + col]);
        unsigned short hi = f2bf(W[(k0 + 2 * jj + 1) * DFEAT + col]);
        o[jj] = (unsigned)lo | ((unsigned)hi << 16);
      }
      uint4 v; v.x = o[0]; v.y = o[1]; v.z = o[2]; v.w = o[3];
      sm.wf[e] = v;
    }
    __syncthreads();
    const short8* Wf8 = (const short8*)sm.wf;
    int wave = t >> 6, lane = t & 63;
    int row0 = gb * GROWS + wave * 16;
    if (row0 < n) {
      int rowA = row0 + (lane & 15);
      if (rowA >= n) rowA = n - 1;  // duplicate last row; stores guarded
      const float4* Xrow = (const float4*)(X + (long long)rowA * DFEAT);
      int koff = (lane >> 4) * 2;

      f32x4 acc[8];
#pragma unroll
      for (int ntp = 0; ntp < 8; ntp++) acc[ntp] = (f32x4){0.f, 0.f, 0.f, 0.f};
#pragma unroll
      for (int kc = 0; kc < 4; kc++) {
        float4 xa = Xrow[kc * 8 + koff];
        float4 xb = Xrow[kc * 8 + koff + 1];
        short8 a8;
        a8[0] = (short)f2bf(xa.x); a8[1] = (short)f2bf(xa.y);
        a8[2] = (short)f2bf(xa.z); a8[3] = (short)f2bf(xa.w);
        a8[4] = (short)f2bf(xb.x); a8[5] = (short)f2bf(xb.y);
        a8[6] = (short)f2bf(xb.z); a8[7] = (short)f2bf(xb.w);
#pragma unroll
        for (int nt = 0; nt < 8; nt++) {
          short8 b8 = Wf8[(kc * 8 + nt) * 64 + lane];
          acc[nt] = __builtin_amdgcn_mfma_f32_16x16x32_bf16(a8, b8, acc[nt], 0, 0, 0);
        }
      }
      int rbase = row0 + (lane >> 4) * 4;
      int cbase = lane & 15;
#pragma unroll
      for (int nt = 0; nt < 8; nt++) {
#pragma unroll
        for (int r = 0; r < 4; r++) {
          int row = rbase + r;
          if (row < n)
            Yh[(long long)row * DFEAT + nt * 16 + cbase] = __float2half(acc[nt][r]);
        }
      }
    }
  }
}

// ---------------- per-bucket counting sort -> adj + start/deg --------------
__global__ __launch_bounds__(1024) void sort_kernel(const unsigned int* __restrict__ bucket,
                                                    const int* __restrict__ gcur,
                                                    int* __restrict__ adj,
                                                    int* __restrict__ start,
                                                    int* __restrict__ degg,
                                                    int n) {
  __shared__ int srt[SORT_CAP];  // 24 KB
  __shared__ int h[BNODES], pref[BNODES], cur[BNODES], scn[BNODES];
  int b = blockIdx.x, t = threadIdx.x;
  int cnt = gcur[b]; if (cnt > SORT_CAP) cnt = SORT_CAP;
  long long base = (long long)b * SORT_CAP;

  if (t < BNODES) h[t] = 0;
  __syncthreads();
  for (int i = t; i < cnt; i += 1024)
    atomicAdd(&h[bucket[base + i] >> 20], 1);
  __syncthreads();
  int v = (t < BNODES) ? h[t] : 0;
  if (t < BNODES) scn[t] = v;
  __syncthreads();
  for (int dd = 1; dd < BNODES; dd <<= 1) {
    int a = (t < BNODES && t >= dd) ? scn[t - dd] : 0;
    __syncthreads();
    if (t < BNODES) scn[t] += a;
    __syncthreads();
  }
  if (t < BNODES) { pref[t] = scn[t] - v; cur[t] = scn[t] - v; }
  __syncthreads();
  for (int i = t; i < cnt; i += 1024) {
    unsigned e = bucket[base + i];
    int p = atomicAdd(&cur[e >> 20], 1);
    srt[p] = (int)(e & 0xFFFFFu);
  }
  __syncthreads();
  for (int i = t; i < cnt; i += 1024) adj[base + i] = srt[i];
  int node = (b << BSH) + t;
  if (t < BNODES && node < n) {
    start[node] = (int)(base + pref[t]);
    degg[node] = h[t];
  }
}

// ---------------- gather + scale + relu (split-wave uint2 loads) ----------
__global__ __launch_bounds__(256) void gather_kernel(const uint2* __restrict__ Yh2,
                                                     const int* __restrict__ start,
                                                     const int* __restrict__ degg,
                                                     const int* __restrict__ adj,
                                                     float4* __restrict__ out4, int n) {
  int wid = (int)((blockIdx.x * (long long)blockDim.x + threadIdx.x) >> 6);
  int lane = threadIdx.x & 63;
  if (wid >= n) return;

  int off0 = start[wid], len = degg[wid];
  int c = lane & 31;
  int half = lane >> 5;
  __half2 acc0 = u2h(0), acc1 = u2h(0), acc2 = u2h(0), acc3 = u2h(0);

  for (int base = 0; base < len; base += 64) {
    int cnt = len - base; if (cnt > 64) cnt = 64;
    int idx = (lane < cnt) ? adj[off0 + base + lane] : 0;
    int tt = 0;
    for (; tt + 16 <= cnt; tt += 16) {  // 16 rows per iter, 8 loads in flight
      uint2 v[8];
#pragma unroll
      for (int u = 0; u < 8; u++) {
        int j = __shfl(idx, tt + 2 * u + half);
        v[u] = Yh2[(long long)j * 32 + c];
      }
      acc0 = __hadd2(acc0, u2h(v[0].x)); acc1 = __hadd2(acc1, u2h(v[0].y));
      acc2 = __hadd2(acc2, u2h(v[1].x)); acc3 = __hadd2(acc3, u2h(v[1].y));
      acc0 = __hadd2(acc0, u2h(v[2].x)); acc1 = __hadd2(acc1, u2h(v[2].y));
      acc2 = __hadd2(acc2, u2h(v[3].x)); acc3 = __hadd2(acc3, u2h(v[3].y));
      acc0 = __hadd2(acc0, u2h(v[4].x)); acc1 = __hadd2(acc1, u2h(v[4].y));
      acc2 = __hadd2(acc2, u2h(v[5].x)); acc3 = __hadd2(acc3, u2h(v[5].y));
      acc0 = __hadd2(acc0, u2h(v[6].x)); acc1 = __hadd2(acc1, u2h(v[6].y));
      acc2 = __hadd2(acc2, u2h(v[7].x)); acc3 = __hadd2(acc3, u2h(v[7].y));
    }
    for (; tt + 2 <= cnt; tt += 2) {  // pair tail
      int j = __shfl(idx, tt + half);
      uint2 v = Yh2[(long long)j * 32 + c];
      acc0 = __hadd2(acc0, u2h(v.x)); acc1 = __hadd2(acc1, u2h(v.y));
    }
    if (tt < cnt) {  // odd tail: zero the upper half's contribution
      int j = __shfl(idx, tt);
      uint2 v = Yh2[(long long)j * 32 + c];
      if (half) { v.x = 0; v.y = 0; }
      acc2 = __hadd2(acc2, u2h(v.x)); acc3 = __hadd2(acc3, u2h(v.y));
    }
  }

  acc0 = __hadd2(acc0, acc2);
  acc1 = __hadd2(acc1, acc3);
  // merge the two half-wave partial sums
  acc0 = __hadd2(acc0, u2h((unsigned)__shfl_xor((int)h2u(acc0), 32)));
  acc1 = __hadd2(acc1, u2h((unsigned)__shfl_xor((int)h2u(acc1), 32)));
  // self row
  uint2 sv = Yh2[(long long)wid * 32 + c];
  acc0 = __hadd2(acc0, u2h(sv.x));
  acc1 = __hadd2(acc1, u2h(sv.y));

  if (half == 0) {
    float2 f0 = __half22float2(acc0);
    float2 f1 = __half22float2(acc1);
    float inv = 1.0f / (float)len;
    float4 o;
    o.x = f0.x * inv; o.y = f0.y * inv; o.z = f1.x * inv; o.w = f1.y * inv;
    o.x = o.x > 0.f ? o.x : 0.f;
    o.y = o.y > 0.f ? o.y : 0.f;
    o.z = o.z > 0.f ? o.z : 0.f;
    o.w = o.w > 0.f ? o.w : 0.f;
    out4[(long long)wid * 32 + c] = o;
  }
}

// ---------------- launch ----------------
extern "C" void kernel_launch(void* const* d_in, const int* in_sizes, int n_in,
                              void* d_out, int out_size, void* d_ws, size_t ws_size,
                              hipStream_t stream) {
  const float* X = (const float*)d_in[0];
  const float* W = (const float*)d_in[1];
  const void* el = d_in[2];
  float* out = (float*)d_out;

  int n = in_sizes[0] / DFEAT;       // 100000
  int E = in_sizes[2] / 2;           // 1600000
  int NB = (n + BNODES - 1) >> BSH;  // 782

  char* p = (char*)d_ws;
  auto alloc = [&](size_t bytes) -> char* {
    char* q = p;
    p += (bytes + 511) & ~(size_t)511;
    return q;
  };
  int* gcur = (int*)alloc((size_t)NBMAX * 4);
  unsigned int* bucket = (unsigned int*)alloc((size_t)NBMAX * SORT_CAP * 4);
  int* adj   = (int*)alloc((size_t)NBMAX * SORT_CAP * 4);
  int* start = (int*)alloc((size_t)n * 4);
  int* degg  = (int*)alloc((size_t)n * 4);
  __half* Yh = (__half*)alloc((size_t)n * DFEAT * 2);

  int SBLKS = (E + EPB - 1) / EPB;       // 391 scatter blocks
  int GBLKS = (n + GROWS - 1) / GROWS;   // 782 gemm blocks

  hipMemsetAsync(gcur, 0, (size_t)NBMAX * 4, stream);
  work_kernel<<<SBLKS + GBLKS, 512, 0, stream>>>(el, gcur, bucket, X, W, Yh,
                                                 E, n, NB, SBLKS);
  sort_kernel<<<NB, 1024, 0, stream>>>(bucket, gcur, adj, start, degg, n);
  gather_kernel<<<(n + 3) / 4, 256, 0, stream>>>((const uint2*)Yh, start, degg, adj,
                                                 (float4*)out, n);
}